// Round 1
// baseline (489.414 us; speedup 1.0000x reference)
//
#include <hip/hip_runtime.h>

#define BATCH 1024
#define TSEQ  512
#define DIN   64
#define H     128
#define NCLS  10
#define BM    16
#define NTHREADS 512

typedef _Float16 h16;
typedef __attribute__((ext_vector_type(8))) _Float16 half8;
typedef __attribute__((ext_vector_type(4))) float f32x4;

__device__ __forceinline__ float sig_f(float x) {
    float t = fminf(-1.4426950408889634f * x, 126.f);
    return __builtin_amdgcn_rcpf(1.f + __builtin_amdgcn_exp2f(t));
}
__device__ __forceinline__ float tanh_f(float x) {
    float t = fminf(-2.8853900817779268f * x, 126.f);
    float e = __builtin_amdgcn_exp2f(t);
    return (1.f - e) * __builtin_amdgcn_rcpf(1.f + e);
}

// Persistent LSTM: 64 blocks x 16 batch rows, 8 waves/block.
// Wave w owns gate columns [16w,16w+16) of each of the 4 gates (g,i,f,o),
// so the c/h update is register-local (same D-fragment layout for all gates).
// Weights held in registers as MFMA B-fragments (96 VGPR/lane).
// LDS: double-buffered A-side staging of x_t (fp16) and h (fp16).
// A/B fragment k-slot mapping: slot(grp=lane>>4, j) -> k = 32*s + 8*grp + j,
// applied identically to A and B (K-permutation invariant => correct result).
// Staging layout: elem (m,k) at addr (k>>3)*128 + m*8 + (k&7)  [halfs]
//   => lane reads its 8 A-elems as one aligned ds_read_b128.
__global__ __launch_bounds__(NTHREADS, 2)
void lstm_persist(const float* __restrict__ x,
                  const float* __restrict__ Wgx, const float* __restrict__ Wgh,
                  const float* __restrict__ Wix, const float* __restrict__ Wih,
                  const float* __restrict__ Wfx, const float* __restrict__ Wfh,
                  const float* __restrict__ Wox, const float* __restrict__ Woh,
                  const float* __restrict__ Wph,
                  const float* __restrict__ bg, const float* __restrict__ bi,
                  const float* __restrict__ bfg, const float* __restrict__ bo,
                  const float* __restrict__ bp,
                  float* __restrict__ out)
{
    __shared__ __align__(16) h16 hbuf[2][H * BM];
    __shared__ __align__(16) h16 xbuf[2][DIN * BM];

    const int tid  = threadIdx.x;
    const int wave = tid >> 6;
    const int lane = tid & 63;
    const int grp  = lane >> 4;
    const int ln   = lane & 15;
    const int b0   = blockIdx.x * BM;
    const int n    = (wave << 4) + ln;   // gate column 0..127 (same for all 4 gates)

    // ---- load weights into register B-fragments (fp32 -> fp16)
    half8 bx[4][2];
    half8 bh[4][4];
    {
        const float* WX[4] = {Wgx, Wix, Wfx, Wox};
        const float* WH[4] = {Wgh, Wih, Wfh, Woh};
        #pragma unroll
        for (int G = 0; G < 4; ++G) {
            #pragma unroll
            for (int s = 0; s < 2; ++s) {
                half8 v;
                #pragma unroll
                for (int j = 0; j < 8; ++j)
                    v[j] = (h16)WX[G][(32*s + 8*grp + j) * H + n];
                bx[G][s] = v;
            }
            #pragma unroll
            for (int s = 0; s < 4; ++s) {
                half8 v;
                #pragma unroll
                for (int j = 0; j < 8; ++j)
                    v[j] = (h16)WH[G][(32*s + 8*grp + j) * H + n];
                bh[G][s] = v;
            }
        }
    }
    float biasv[4];
    biasv[0] = bg[n]; biasv[1] = bi[n]; biasv[2] = bfg[n]; biasv[3] = bo[n];

    // ---- zero h state, stage x[0] into xbuf[0]
    #pragma unroll
    for (int i = tid; i < H * BM; i += NTHREADS) hbuf[0][i] = (h16)0.f;
    const int xm = tid >> 5;              // row 0..15
    const int xk = (tid & 31) * 2;        // k 0,2,..,62
    {
        const float* xp = x + ((size_t)(b0 + xm) * TSEQ) * DIN + xk;
        float a0 = xp[0], a1 = xp[1];
        int ad = ((xk >> 3) << 7) + xm * 8 + (xk & 7);
        xbuf[0][ad] = (h16)a0; xbuf[0][ad + 1] = (h16)a1;
    }

    f32x4 cstate = {0.f, 0.f, 0.f, 0.f};
    const int hw_base = ((n >> 3) << 7) + (n & 7);   // h write base for col n
    const int fr_off  = (ln << 3);                   // A-frag per-lane offset

    for (int t = 0; t < TSEQ; ++t) {
        const int p = t & 1;
        __syncthreads();

        // prefetch x[t+1] (clamped on last iter; redundant but harmless)
        const int tn = (t + 1 < TSEQ) ? (t + 1) : t;
        const float* xp = x + ((size_t)(b0 + xm) * TSEQ + tn) * DIN + xk;
        const float a0 = xp[0];
        const float a1 = xp[1];

        // A fragments (shared across the 4 gates)
        half8 ax0 = *(const half8*)&xbuf[p][((0*4 + grp) << 7) + fr_off];
        half8 ax1 = *(const half8*)&xbuf[p][((1*4 + grp) << 7) + fr_off];
        half8 ah0 = *(const half8*)&hbuf[p][((0*4 + grp) << 7) + fr_off];
        half8 ah1 = *(const half8*)&hbuf[p][((1*4 + grp) << 7) + fr_off];
        half8 ah2 = *(const half8*)&hbuf[p][((2*4 + grp) << 7) + fr_off];
        half8 ah3 = *(const half8*)&hbuf[p][((3*4 + grp) << 7) + fr_off];

        f32x4 acc[4];
        #pragma unroll
        for (int G = 0; G < 4; ++G) {
            f32x4 a = {biasv[G], biasv[G], biasv[G], biasv[G]};
            a = __builtin_amdgcn_mfma_f32_16x16x32_f16(ax0, bx[G][0], a, 0, 0, 0);
            a = __builtin_amdgcn_mfma_f32_16x16x32_f16(ax1, bx[G][1], a, 0, 0, 0);
            a = __builtin_amdgcn_mfma_f32_16x16x32_f16(ah0, bh[G][0], a, 0, 0, 0);
            a = __builtin_amdgcn_mfma_f32_16x16x32_f16(ah1, bh[G][1], a, 0, 0, 0);
            a = __builtin_amdgcn_mfma_f32_16x16x32_f16(ah2, bh[G][2], a, 0, 0, 0);
            a = __builtin_amdgcn_mfma_f32_16x16x32_f16(ah3, bh[G][3], a, 0, 0, 0);
            acc[G] = a;
        }

        // gate nonlinearities + state update (all register-local)
        f32x4 hv;
        #pragma unroll
        for (int r = 0; r < 4; ++r) {
            float gv = tanh_f(acc[0][r]);
            float iv = sig_f(acc[1][r]);
            float fv = sig_f(acc[2][r]);
            float ov = sig_f(acc[3][r]);
            float c  = gv * iv + cstate[r] * fv;
            cstate[r] = c;
            hv[r] = tanh_f(c) * ov;
        }

        // write h(t) to the other buffer (row = 4*grp + r, col = n)
        h16* hw = hbuf[p ^ 1];
        #pragma unroll
        for (int r = 0; r < 4; ++r)
            hw[hw_base + (((grp << 2) + r) << 3)] = (h16)hv[r];

        // write x prefetch to the other buffer
        {
            int ad = ((xk >> 3) << 7) + xm * 8 + (xk & 7);
            xbuf[p ^ 1][ad]     = (h16)a0;
            xbuf[p ^ 1][ad + 1] = (h16)a1;
        }
    }

    __syncthreads();
    // final h is in hbuf[0] (written at end of step t=511)
    if (tid < BM * NCLS) {
        const int m = tid / NCLS;
        const int cls = tid - m * NCLS;
        float s = bp[cls];
        #pragma unroll 8
        for (int k = 0; k < H; ++k) {
            float hvv = (float)hbuf[0][((k >> 3) << 7) + m * 8 + (k & 7)];
            s += hvv * Wph[k * NCLS + cls];
        }
        out[(size_t)(b0 + m) * NCLS + cls] = s;
    }
}

extern "C" void kernel_launch(void* const* d_in, const int* in_sizes, int n_in,
                              void* d_out, int out_size, void* d_ws, size_t ws_size,
                              hipStream_t stream) {
    (void)in_sizes; (void)n_in; (void)d_ws; (void)ws_size; (void)out_size;
    lstm_persist<<<dim3(BATCH / BM), dim3(NTHREADS), 0, stream>>>(
        (const float*)d_in[0],
        (const float*)d_in[1], (const float*)d_in[2],
        (const float*)d_in[3], (const float*)d_in[4],
        (const float*)d_in[5], (const float*)d_in[6],
        (const float*)d_in[7], (const float*)d_in[8],
        (const float*)d_in[9],
        (const float*)d_in[10], (const float*)d_in[11],
        (const float*)d_in[12], (const float*)d_in[13],
        (const float*)d_in[14],
        (float*)d_out);
}

// Round 3
// 451.118 us; speedup vs baseline: 1.0849x; 1.0849x over previous
//
#include <hip/hip_runtime.h>

#define BATCH 1024
#define TSEQ  512
#define DIN   64
#define H     128
#define NCLS  10
#define BM    16
#define NTHREADS 512

typedef _Float16 h16;
typedef __attribute__((ext_vector_type(4))) _Float16 half4v;
typedef __attribute__((ext_vector_type(8))) _Float16 half8v;
typedef __attribute__((ext_vector_type(4))) float f32x4;

// Swizzled staging layout (units: halfs) for a 16-row x K-col fp16 tile.
// chunk(m, kg) = kg*16 + (m ^ (kg&7)); element (m,k) at chunk*8 + (k&7).
// - A-frag read: lane(ln,grp) reads chunk(ln, 4s+grp) as one aligned b128.
//   Per instr the 64 chunks are distinct & cover 1024B -> conflict-free.
// - h-write (col n fixed, m varying): XOR spreads chunks -> <=2-way (free).
// - x-write (b64 per thread): <=2-way (free).
__device__ __forceinline__ int stg_addr(int m, int k) {
    const int kg = k >> 3;
    return (((kg << 4) + (m ^ (kg & 7))) << 3) + (k & 7);
}

__device__ __forceinline__ half4v pack4(float a, float b, float c, float d) {
    half4v v;
    v[0] = (h16)a; v[1] = (h16)b; v[2] = (h16)c; v[3] = (h16)d;
    return v;
}

// Clamp-free: rcp(inf)=0 handles saturation; no NaN for finite x.
__device__ __forceinline__ float sig_f(float x) {
    return __builtin_amdgcn_rcpf(1.f + __builtin_amdgcn_exp2f(x * -1.4426950408889634f));
}
__device__ __forceinline__ float tanh_f(float x) {
    float t = __builtin_amdgcn_rcpf(1.f + __builtin_amdgcn_exp2f(x * -2.8853900817779268f));
    return __builtin_fmaf(2.f, t, -1.f);
}

// Persistent LSTM: 64 blocks x 16 batch rows, 8 waves/block.
// Wave w owns gate columns [16w,16w+16) of all 4 gates -> c/h update is
// register-local. Weights live in registers as MFMA B-fragments.
// LDS: double-buffered swizzled fp16 staging of x_t (2KB) and h (4KB).
__global__ __launch_bounds__(NTHREADS, 2)
void lstm_persist(const float* __restrict__ x,
                  const float* __restrict__ Wgx, const float* __restrict__ Wgh,
                  const float* __restrict__ Wix, const float* __restrict__ Wih,
                  const float* __restrict__ Wfx, const float* __restrict__ Wfh,
                  const float* __restrict__ Wox, const float* __restrict__ Woh,
                  const float* __restrict__ Wph,
                  const float* __restrict__ bg, const float* __restrict__ bi,
                  const float* __restrict__ bfg, const float* __restrict__ bo,
                  const float* __restrict__ bp,
                  float* __restrict__ out)
{
    __shared__ __align__(16) h16 hbuf[2][H * BM];    // 2 x 4KB
    __shared__ __align__(16) h16 xbuf[2][DIN * BM];  // 2 x 2KB

    const int tid  = threadIdx.x;
    const int wave = tid >> 6;
    const int lane = tid & 63;
    const int grp  = lane >> 4;
    const int ln   = lane & 15;
    const int b0   = blockIdx.x * BM;
    const int n    = (wave << 4) + ln;   // gate column 0..127

    // ---- weights -> register B-fragments (fp32 -> fp16)
    half8v bx[4][2];
    half8v bh[4][4];
    {
        const float* WX[4] = {Wgx, Wix, Wfx, Wox};
        const float* WH[4] = {Wgh, Wih, Wfh, Woh};
        #pragma unroll
        for (int G = 0; G < 4; ++G) {
            #pragma unroll
            for (int s = 0; s < 2; ++s) {
                half8v v;
                #pragma unroll
                for (int j = 0; j < 8; ++j)
                    v[j] = (h16)WX[G][(32*s + 8*grp + j) * H + n];
                bx[G][s] = v;
            }
            #pragma unroll
            for (int s = 0; s < 4; ++s) {
                half8v v;
                #pragma unroll
                for (int j = 0; j < 8; ++j)
                    v[j] = (h16)WH[G][(32*s + 8*grp + j) * H + n];
                bh[G][s] = v;
            }
        }
    }
    // bias splats used directly as the C operand of the first MFMA per gate
    f32x4 bias_c[4];
    {
        const float bv[4] = {bg[n], bi[n], bfg[n], bo[n]};
        #pragma unroll
        for (int G = 0; G < 4; ++G)
            bias_c[G] = (f32x4){bv[G], bv[G], bv[G], bv[G]};
    }

    // ---- zero h(0); stage x[0]; preload x[1] (2-step-deep x pipeline)
    *(half4v*)&hbuf[0][tid << 2] = (half4v)0;

    const int xm  = tid >> 4;             // 0..15 (threads 0..255 stage x)
    const int xk0 = (tid & 15) << 2;      // 0,4,...,60
    const int xwr = stg_addr(xm, xk0);
    const float* xrow = x + (size_t)(b0 + xm) * TSEQ * DIN + xk0;

    f32x4 xhold = {0.f, 0.f, 0.f, 0.f};
    f32x4 xnew  = {0.f, 0.f, 0.f, 0.f};
    if (tid < 256) {
        f32x4 x0 = *(const f32x4*)xrow;
        *(half4v*)&xbuf[0][xwr] = pack4(x0[0], x0[1], x0[2], x0[3]);
        xhold = *(const f32x4*)(xrow + DIN);   // x[1]
        xnew  = xhold;
    }

    // hoisted h-write addresses (element (4*grp+r, n) of the staging tile)
    int hwr[4];
    #pragma unroll
    for (int r = 0; r < 4; ++r) hwr[r] = stg_addr((grp << 2) + r, n);

    f32x4 cstate = {0.f, 0.f, 0.f, 0.f};

    #pragma unroll 2
    for (int t = 0; t < TSEQ; ++t) {
        const int p = t & 1;
        __syncthreads();

        // issue x[t+2] early; consumed (LDS write) one full step later
        if (tid < 256 && t + 2 < TSEQ)
            xnew = *(const f32x4*)(xrow + (size_t)(t + 2) * DIN);

        // A fragments (shared by the 4 gates); slot k = 32s + 8*grp + j
        half8v ax0 = *(const half8v*)&xbuf[p][stg_addr(ln,      8 * grp)];
        half8v ax1 = *(const half8v*)&xbuf[p][stg_addr(ln, 32 + 8 * grp)];
        half8v ah0 = *(const half8v*)&hbuf[p][stg_addr(ln,      8 * grp)];
        half8v ah1 = *(const half8v*)&hbuf[p][stg_addr(ln, 32 + 8 * grp)];
        half8v ah2 = *(const half8v*)&hbuf[p][stg_addr(ln, 64 + 8 * grp)];
        half8v ah3 = *(const half8v*)&hbuf[p][stg_addr(ln, 96 + 8 * grp)];

        f32x4 acc[4];
        #pragma unroll
        for (int G = 0; G < 4; ++G) {
            f32x4 a = __builtin_amdgcn_mfma_f32_16x16x32_f16(ax0, bx[G][0], bias_c[G], 0, 0, 0);
            a = __builtin_amdgcn_mfma_f32_16x16x32_f16(ax1, bx[G][1], a, 0, 0, 0);
            a = __builtin_amdgcn_mfma_f32_16x16x32_f16(ah0, bh[G][0], a, 0, 0, 0);
            a = __builtin_amdgcn_mfma_f32_16x16x32_f16(ah1, bh[G][1], a, 0, 0, 0);
            a = __builtin_amdgcn_mfma_f32_16x16x32_f16(ah2, bh[G][2], a, 0, 0, 0);
            a = __builtin_amdgcn_mfma_f32_16x16x32_f16(ah3, bh[G][3], a, 0, 0, 0);
            acc[G] = a;
        }

        // write x(t+1) (loaded last iteration -> no vmcnt stall)
        if (tid < 256)
            *(half4v*)&xbuf[p ^ 1][xwr] = pack4(xhold[0], xhold[1], xhold[2], xhold[3]);
        xhold = xnew;

        // gate nonlinearities + state update (register-local)
        f32x4 hv;
        #pragma unroll
        for (int r = 0; r < 4; ++r) {
            float gv = tanh_f(acc[0][r]);
            float iv = sig_f(acc[1][r]);
            float fv = sig_f(acc[2][r]);
            float ov = sig_f(acc[3][r]);
            float c  = __builtin_fmaf(cstate[r], fv, gv * iv);
            cstate[r] = c;
            hv[r] = tanh_f(c) * ov;
        }

        // write h(t+1) to the other buffer
        h16* hw = hbuf[p ^ 1];
        #pragma unroll
        for (int r = 0; r < 4; ++r)
            hw[hwr[r]] = (h16)hv[r];
    }

    __syncthreads();
    // final h is in hbuf[0] (t=511 writes p^1 = 0)
    if (tid < BM * NCLS) {
        const int m = tid / NCLS;
        const int cls = tid - m * NCLS;
        float s = bp[cls];
        #pragma unroll 8
        for (int k = 0; k < H; ++k) {
            float hvv = (float)hbuf[0][stg_addr(m, k)];
            s += hvv * Wph[k * NCLS + cls];
        }
        out[(size_t)(b0 + m) * NCLS + cls] = s;
    }
}

extern "C" void kernel_launch(void* const* d_in, const int* in_sizes, int n_in,
                              void* d_out, int out_size, void* d_ws, size_t ws_size,
                              hipStream_t stream) {
    (void)in_sizes; (void)n_in; (void)d_ws; (void)ws_size; (void)out_size;
    lstm_persist<<<dim3(BATCH / BM), dim3(NTHREADS), 0, stream>>>(
        (const float*)d_in[0],
        (const float*)d_in[1], (const float*)d_in[2],
        (const float*)d_in[3], (const float*)d_in[4],
        (const float*)d_in[5], (const float*)d_in[6],
        (const float*)d_in[7], (const float*)d_in[8],
        (const float*)d_in[9],
        (const float*)d_in[10], (const float*)d_in[11],
        (const float*)d_in[12], (const float*)d_in[13],
        (const float*)d_in[14],
        (float*)d_out);
}